// Round 5
// baseline (377.270 us; speedup 1.0000x reference)
//
#include <hip/hip_runtime.h>
#include <hip/hip_bf16.h>

#define BGR 4096      // graphs per side
#define DIM 256
#define CHG 1024      // graphs per chunk
#define HS  257       // LDS row stride for rel_kernel (fp32)

typedef __bf16 bf16x8 __attribute__((ext_vector_type(8)));
typedef __bf16 bf16x4 __attribute__((ext_vector_type(4)));
typedef float  f32x4  __attribute__((ext_vector_type(4)));

__device__ __forceinline__ unsigned short f2b(float f) {
  unsigned u = __builtin_bit_cast(unsigned, f);
  u = (u + 0x7FFFu + ((u >> 16) & 1u)) >> 16;   // RNE
  return (unsigned short)u;
}

__device__ __forceinline__ bf16x8 cvt8(float4 a, float4 b) {
  bf16x8 r;
  r[0] = (__bf16)a.x; r[1] = (__bf16)a.y; r[2] = (__bf16)a.z; r[3] = (__bf16)a.w;
  r[4] = (__bf16)b.x; r[5] = (__bf16)b.y; r[6] = (__bf16)b.z; r[7] = (__bf16)b.w;
  return r;
}
__device__ __forceinline__ bf16x4 cvt4(f32x4 c) {
  bf16x4 r;
  r[0] = (__bf16)c[0]; r[1] = (__bf16)c[1]; r[2] = (__bf16)c[2]; r[3] = (__bf16)c[3];
  return r;
}

// ---------------------------------------------------------------------------
// Weight prep: W1b = [WO1;WI1] bf16 [128 rows][256 k], W2b = [WO2|WI2] bf16
// [256 rows][128 k], b1 = bO1+bI1 (f32[64]), b2 = bO2+bI2 (f32[256]).
// ---------------------------------------------------------------------------
__global__ void wcvt_kernel(
    const float* __restrict__ WO1, const float* __restrict__ WI1,
    const float* __restrict__ WO2, const float* __restrict__ WI2,
    const float* __restrict__ bO1, const float* __restrict__ bI1,
    const float* __restrict__ bO2, const float* __restrict__ bI2,
    unsigned short* __restrict__ W1b, unsigned short* __restrict__ W2b,
    float* __restrict__ b1, float* __restrict__ b2)
{
  const int i = blockIdx.x * 256 + threadIdx.x;   // 0..32767
  { int j = i >> 8, k = i & 255;
    float v = (j < 64) ? WO1[j * 256 + k] : WI1[(j - 64) * 256 + k];
    W1b[i] = f2b(v); }
  { int j = i >> 7, k = i & 127;
    float v = (k < 64) ? WO2[j * 64 + k] : WI2[j * 64 + (k - 64)];
    W2b[i] = f2b(v); }
  if (i < 64)  b1[i] = bO1[i] + bI1[i];
  if (i < 256) b2[i] = bO2[i] + bI2[i];
}

// ---------------------------------------------------------------------------
// gemm0: Yt[g][j=128][node=32] = (E @ W1cat^T)^T  for one chunk of CHG graphs.
// Pure streaming GEMM: no LDS, no barriers. Block = 64 rows (2 graphs),
// wave w: row-half h = w>>1 (32 rows), j-half jh = w&1 (64 j).
// ---------------------------------------------------------------------------
__global__ __launch_bounds__(256) void gemm0_kernel(
    const float* __restrict__ E, const unsigned short* __restrict__ W1b,
    unsigned short* __restrict__ Yt)
{
  const int t = threadIdx.x, w = t >> 6, l = t & 63;
  const int ln16 = l & 15, kg = l >> 4;
  const int h = w >> 1, jh = w & 1;
  const size_t row0 = (size_t)blockIdx.x * 64 + h * 32;

  f32x4 acc[2][4];
  #pragma unroll
  for (int mt = 0; mt < 2; mt++)
    #pragma unroll
    for (int nt = 0; nt < 4; nt++) { f32x4 z = {0.f, 0.f, 0.f, 0.f}; acc[mt][nt] = z; }

  const float* ea = E + (row0 + ln16) * DIM + kg * 8;
  const unsigned short* wb = W1b + (jh * 64 + ln16) * 256 + kg * 8;

  #pragma unroll
  for (int ks = 0; ks < 8; ks++) {
    bf16x8 B[4];
    #pragma unroll
    for (int nt = 0; nt < 4; nt++)
      B[nt] = *(const bf16x8*)(wb + nt * 4096 + ks * 32);
    #pragma unroll
    for (int mt = 0; mt < 2; mt++) {
      float4 a0 = *(const float4*)(ea + mt * 4096 + ks * 32);
      float4 a1 = *(const float4*)(ea + mt * 4096 + ks * 32 + 4);
      bf16x8 A = cvt8(a0, a1);
      #pragma unroll
      for (int nt = 0; nt < 4; nt++)
        acc[mt][nt] = __builtin_amdgcn_mfma_f32_16x16x32_bf16(A, B[nt], acc[mt][nt], 0, 0, 0);
    }
  }
  // C[m=row][n=j] -> Yt[g][j][node]; g = blk*2+h, node = mt*16+kg*4+i
  unsigned short* yo = Yt + ((size_t)(blockIdx.x * 2 + h) * 128 + jh * 64 + ln16) * 32 + kg * 4;
  #pragma unroll
  for (int mt = 0; mt < 2; mt++)
    #pragma unroll
    for (int nt = 0; nt < 4; nt++)
      *(bf16x4*)(yo + nt * 512 + mt * 16) = cvt4(acc[mt][nt]);
}

// ---------------------------------------------------------------------------
// graph_bc: one WAVE per graph, no barriers. Per wave:
//  counts (packed-byte LDS atomics) -> M frags (regs) -> step1 (B from Yt
//  global) -> H1T (wave-private LDS) -> step2 -> A2 written over Yt[g] ->
//  step3 (W2 from L2) + fused mean readout.
// LDS per wave: 256 u32 cnt + 32 deg_in + 32 deg_out (1280 B) + H1T 64x72B.
// ---------------------------------------------------------------------------
__global__ __launch_bounds__(256) void graph_bc_kernel(
    unsigned short* __restrict__ Yt,
    const int* __restrict__ srcp, const int* __restrict__ dstp,
    const unsigned short* __restrict__ W2b,
    const float* __restrict__ b1, const float* __restrict__ b2,
    float* __restrict__ gout)
{
  __shared__ __align__(16) unsigned char S[23552];
  const int t = threadIdx.x, w = t >> 6, l = t & 63;
  const int ln16 = l & 15, kg = l >> 4;
  const int g = blockIdx.x * 4 + w;
  unsigned* cw = (unsigned*)(S + w * 5888);
  unsigned char* h1t = S + w * 5888 + 1280;

  // edge loads (issue early)
  const int eb = g * 128 + l;
  const int s0 = srcp[eb] & 31, s1 = srcp[eb + 64] & 31;
  const int d0 = dstp[eb] & 31, d1 = dstp[eb + 64] & 31;

  // step1 B-frags from Yt (issue early; independent of counts)
  unsigned short* yg = Yt + (size_t)g * 4096;
  bf16x8 Bo[4], Bi[4];
  #pragma unroll
  for (int nt = 0; nt < 4; nt++) {
    Bo[nt] = *(const bf16x8*)(yg + (nt * 16 + ln16) * 32 + kg * 8);
    Bi[nt] = *(const bf16x8*)(yg + (64 + nt * 16 + ln16) * 32 + kg * 8);
  }
  float b1j[4];
  #pragma unroll
  for (int nt = 0; nt < 4; nt++) b1j[nt] = b1[nt * 16 + ln16];

  // zero counts, then count (wave-synchronous program order; wave-private LDS)
  #pragma unroll
  for (int i = 0; i < 5; i++) cw[l + i * 64] = 0u;
  atomicAdd(&cw[d0 * 8 + (s0 >> 2)], 1u << ((s0 & 3) * 8));
  atomicAdd(&cw[d1 * 8 + (s1 >> 2)], 1u << ((s1 & 3) * 8));
  atomicAdd(&cw[256 + d0], 1u); atomicAdd(&cw[256 + d1], 1u);
  atomicAdd(&cw[288 + s0], 1u); atomicAdd(&cw[288 + s1], 1u);

  // M fragments in registers
  bf16x8 m1f[2], m2f[2];
  #pragma unroll
  for (int hf = 0; hf < 2; hf++) {
    const int r = hf * 16 + ln16;
    const float fi = 1.0f / fmaxf((float)cw[256 + r], 1.0f);
    const float fo = 1.0f / fmaxf((float)cw[288 + r], 1.0f);
    const unsigned w0 = cw[r * 8 + kg * 2], w1 = cw[r * 8 + kg * 2 + 1];
    bf16x8 a, b;
    #pragma unroll
    for (int q = 0; q < 4; q++) {
      a[q]     = (__bf16)((float)((w0 >> (q * 8)) & 255u) * fi);
      a[4 + q] = (__bf16)((float)((w1 >> (q * 8)) & 255u) * fi);
    }
    #pragma unroll
    for (int q = 0; q < 8; q++) {
      const unsigned wq = cw[(kg * 8 + q) * 8 + (r >> 2)];
      b[q] = (__bf16)((float)((wq >> ((r & 3) * 8)) & 255u) * fo);
    }
    m1f[hf] = a; m2f[hf] = b;
  }

  // step1: H1[dst][j64] = relu(M1@Yo + M2@Yi + b1) -> H1T[j][dst] in LDS
  #pragma unroll
  for (int mt = 0; mt < 2; mt++)
    #pragma unroll
    for (int nt = 0; nt < 4; nt++) {
      f32x4 z = {0.f, 0.f, 0.f, 0.f};
      f32x4 c = __builtin_amdgcn_mfma_f32_16x16x32_bf16(m1f[mt], Bo[nt], z, 0, 0, 0);
      c = __builtin_amdgcn_mfma_f32_16x16x32_bf16(m2f[mt], Bi[nt], c, 0, 0, 0);
      f32x4 hv = { fmaxf(c[0] + b1j[nt], 0.f), fmaxf(c[1] + b1j[nt], 0.f),
                   fmaxf(c[2] + b1j[nt], 0.f), fmaxf(c[3] + b1j[nt], 0.f) };
      *(bf16x4*)(h1t + (nt * 16 + ln16) * 72 + (mt * 16 + kg * 4) * 2) = cvt4(hv);
    }

  // step2: A2[dst][128] = [M1@H1 | M2@H1], written over Yt[g] (dead)
  #pragma unroll
  for (int mta = 0; mta < 4; mta++) {
    bf16x8 Af = *(const bf16x8*)(h1t + (mta * 16 + ln16) * 72 + kg * 16);
    #pragma unroll
    for (int hf = 0; hf < 2; hf++)
      #pragma unroll
      for (int ntd = 0; ntd < 2; ntd++) {
        f32x4 z = {0.f, 0.f, 0.f, 0.f};
        f32x4 c = __builtin_amdgcn_mfma_f32_16x16x32_bf16(
            Af, hf ? m2f[ntd] : m1f[ntd], z, 0, 0, 0);
        *(bf16x4*)(yg + (ntd * 16 + ln16) * 128 + hf * 64 + mta * 16 + kg * 4) = cvt4(c);
      }
  }
  asm volatile("s_waitcnt vmcnt(0)" ::: "memory");   // same-wave global RAW

  // step3: H2 = relu(A2 @ W2cat^T + b2), fused mean over 32 nodes
  bf16x8 BF[2][4];
  #pragma unroll
  for (int ntd = 0; ntd < 2; ntd++)
    #pragma unroll
    for (int ks = 0; ks < 4; ks++)
      BF[ntd][ks] = *(const bf16x8*)(yg + (ntd * 16 + ln16) * 128 + ks * 32 + kg * 8);

  #pragma unroll
  for (int mt = 0; mt < 16; mt++) {
    bf16x8 AW[4];
    #pragma unroll
    for (int ks = 0; ks < 4; ks++)
      AW[ks] = *(const bf16x8*)(W2b + (mt * 16 + ln16) * 128 + ks * 32 + kg * 8);
    f32x4 a0 = {0.f, 0.f, 0.f, 0.f}, a1 = {0.f, 0.f, 0.f, 0.f};
    #pragma unroll
    for (int ks = 0; ks < 4; ks++) {
      a0 = __builtin_amdgcn_mfma_f32_16x16x32_bf16(AW[ks], BF[0][ks], a0, 0, 0, 0);
      a1 = __builtin_amdgcn_mfma_f32_16x16x32_bf16(AW[ks], BF[1][ks], a1, 0, 0, 0);
    }
    const float4 bb = *(const float4*)(b2 + mt * 16 + kg * 4);
    float v0 = fmaxf(a0[0] + bb.x, 0.f) + fmaxf(a1[0] + bb.x, 0.f);
    float v1 = fmaxf(a0[1] + bb.y, 0.f) + fmaxf(a1[1] + bb.y, 0.f);
    float v2 = fmaxf(a0[2] + bb.z, 0.f) + fmaxf(a1[2] + bb.z, 0.f);
    float v3 = fmaxf(a0[3] + bb.w, 0.f) + fmaxf(a1[3] + bb.w, 0.f);
    #pragma unroll
    for (int d = 1; d < 16; d <<= 1) {
      v0 += __shfl_xor(v0, d); v1 += __shfl_xor(v1, d);
      v2 += __shfl_xor(v2, d); v3 += __shfl_xor(v3, d);
    }
    if (ln16 == 0) {
      float4 o = { v0 * 0.03125f, v1 * 0.03125f, v2 * 0.03125f, v3 * 0.03125f };
      *(float4*)(gout + (size_t)g * DIM + mt * 16 + kg * 4) = o;
    }
  }
}

// ---------------------------------------------------------------------------
// r_embs = relu(rel @ relW.T + relb). 16 rows per block. (fp32 VALU)
// ---------------------------------------------------------------------------
__global__ __launch_bounds__(256, 4) void rel_kernel(
    const float* __restrict__ rel, const float* __restrict__ relW,
    const float* __restrict__ relb, float* __restrict__ r_out)
{
  __shared__ float srel[16 * HS];
  const int t = threadIdx.x;
  const int b0 = blockIdx.x << 4;
  #pragma unroll
  for (int i = 0; i < 4; i++) {
    int f = (i << 8) + t;
    int r = f >> 6, k4 = f & 63;
    float4 x = *(const float4*)(rel + (size_t)(b0 + r) * DIM + (k4 << 2));
    float* d = &srel[r * HS + (k4 << 2)];
    d[0] = x.x; d[1] = x.y; d[2] = x.z; d[3] = x.w;
  }
  __syncthreads();
  const int r = t & 15, jg = t >> 4;
  const float* pa = &srel[r * HS];
  const float* w = relW + (size_t)(jg * 16) * DIM;
  float acc[16];
  #pragma unroll
  for (int jj = 0; jj < 16; jj++) acc[jj] = 0.f;
  for (int k0 = 0; k0 < DIM; k0 += 16) {
    float a[16];
    #pragma unroll
    for (int u = 0; u < 16; u++) a[u] = pa[k0 + u];
    #pragma unroll
    for (int jj = 0; jj < 16; jj++) {
      const float* wr = w + jj * DIM + k0;
      #pragma unroll
      for (int u = 0; u < 16; u += 4) {
        float4 wv = *(const float4*)(wr + u);
        acc[jj] += a[u]*wv.x + a[u+1]*wv.y + a[u+2]*wv.z + a[u+3]*wv.w;
      }
    }
  }
  float* outp = r_out + (size_t)(b0 + r) * DIM + jg * 16;
  #pragma unroll
  for (int jj = 0; jj < 16; jj++) outp[jj] = fmaxf(acc[jj] + relb[jg * 16 + jj], 0.f);
}

// ---------------------------------------------------------------------------
// Distances: pos = ||h+r-t||, neg = ||h[ch]+r-t[ct]||. One wave per triple.
// ---------------------------------------------------------------------------
__global__ __launch_bounds__(256) void dist_kernel(
    const float* __restrict__ hemb, const float* __restrict__ temb,
    const float* __restrict__ remb, const int* __restrict__ chx,
    const int* __restrict__ ctx, float* __restrict__ out)
{
  const int t = threadIdx.x;
  const int w = t >> 6, l = t & 63;
  const int b = (blockIdx.x << 2) + w;
  float4 h4 = *(const float4*)(hemb + (size_t)b * DIM + (l << 2));
  float4 r4 = *(const float4*)(remb + (size_t)b * DIM + (l << 2));
  float4 t4 = *(const float4*)(temb + (size_t)b * DIM + (l << 2));
  int hb = chx[b], tb = ctx[b];
  float4 hn = *(const float4*)(hemb + (size_t)hb * DIM + (l << 2));
  float4 tn = *(const float4*)(temb + (size_t)tb * DIM + (l << 2));
  float x0 = h4.x + r4.x - t4.x, x1 = h4.y + r4.y - t4.y;
  float x2 = h4.z + r4.z - t4.z, x3 = h4.w + r4.w - t4.w;
  float dp = x0*x0 + x1*x1 + x2*x2 + x3*x3;
  float y0 = hn.x + r4.x - tn.x, y1 = hn.y + r4.y - tn.y;
  float y2 = hn.z + r4.z - tn.z, y3 = hn.w + r4.w - tn.w;
  float dn = y0*y0 + y1*y1 + y2*y2 + y3*y3;
  #pragma unroll
  for (int off = 32; off >= 1; off >>= 1) {
    dp += __shfl_down(dp, off);
    dn += __shfl_down(dn, off);
  }
  if (l == 0) {
    out[b] = sqrtf(dp);
    out[BGR + b] = sqrtf(dn);
  }
}

extern "C" void kernel_launch(void* const* d_in, const int* in_sizes, int n_in,
                              void* d_out, int out_size, void* d_ws, size_t ws_size,
                              hipStream_t stream) {
  const float* subj_embs = (const float*)d_in[0];
  const float* obj_embs  = (const float*)d_in[1];
  const float* rel_tok   = (const float*)d_in[2];
  const int* subj_src = (const int*)d_in[3];
  const int* subj_dst = (const int*)d_in[4];
  const int* obj_src  = (const int*)d_in[5];
  const int* obj_dst  = (const int*)d_in[6];
  // d_in[7] = node_graph_ids (implicit by construction)
  const int* chx = (const int*)d_in[8];
  const int* ctx = (const int*)d_in[9];
  const float* WO1 = (const float*)d_in[10];
  const float* bO1 = (const float*)d_in[11];
  const float* WI1 = (const float*)d_in[12];
  const float* bI1 = (const float*)d_in[13];
  const float* WO2 = (const float*)d_in[14];
  const float* bO2 = (const float*)d_in[15];
  const float* WI2 = (const float*)d_in[16];
  const float* bI2 = (const float*)d_in[17];
  const float* relW = (const float*)d_in[18];
  const float* relb = (const float*)d_in[19];

  float* g_embs = (float*)d_ws;                           // [8192,256] f32 = 8 MB
  float* r_embs = g_embs + (size_t)2 * BGR * DIM;         // [4096,256] f32 = 4 MB
  unsigned short* W1b = (unsigned short*)((char*)d_ws + 12582912);  // 64 KB
  unsigned short* W2b = W1b + 32768;                                // 64 KB
  float* b1 = (float*)((char*)d_ws + 12713984);                     // 256 B
  float* b2 = b1 + 64;                                              // 1 KB
  unsigned short* Ytbuf = (unsigned short*)((char*)d_ws + 12715264);// 8 MB chunk
  float* out = (float*)d_out;                             // [8192]: pos | neg

  wcvt_kernel<<<128, 256, 0, stream>>>(WO1, WI1, WO2, WI2, bO1, bI1, bO2, bI2,
                                       W1b, W2b, b1, b2);

  for (int c = 0; c < 8; c++) {
    const int side = c >> 2;
    const size_t gbase = (size_t)(c & 3) * CHG;
    const float* E = (side ? obj_embs : subj_embs) + gbase * 32 * DIM;
    const int* sp = (side ? obj_src : subj_src) + gbase * 128;
    const int* dp = (side ? obj_dst : subj_dst) + gbase * 128;
    float* go = g_embs + ((size_t)side * BGR + gbase) * DIM;
    gemm0_kernel<<<CHG / 2, 256, 0, stream>>>(E, W1b, Ytbuf);
    graph_bc_kernel<<<CHG / 4, 256, 0, stream>>>(Ytbuf, sp, dp, W2b, b1, b2, go);
  }

  rel_kernel<<<BGR / 16, 256, 0, stream>>>(rel_tok, relW, relb, r_embs);
  dist_kernel<<<BGR / 4, 256, 0, stream>>>(
      g_embs, g_embs + (size_t)BGR * DIM, r_embs, chx, ctx, out);
}

// Round 6
// 291.813 us; speedup vs baseline: 1.2929x; 1.2929x over previous
//
#include <hip/hip_runtime.h>
#include <hip/hip_bf16.h>

#define BGR 4096      // graphs per side
#define DIM 256
#define HS  257       // LDS row stride for rel_kernel (fp32)

typedef __bf16 bf16x8 __attribute__((ext_vector_type(8)));
typedef __bf16 bf16x4 __attribute__((ext_vector_type(4)));
typedef float  f32x4  __attribute__((ext_vector_type(4)));

__device__ __forceinline__ unsigned short f2b(float f) {
  unsigned u = __builtin_bit_cast(unsigned, f);
  u = (u + 0x7FFFu + ((u >> 16) & 1u)) >> 16;   // RNE
  return (unsigned short)u;
}

__device__ __forceinline__ bf16x8 cvt8(float4 a, float4 b) {
  bf16x8 r;
  r[0] = (__bf16)a.x; r[1] = (__bf16)a.y; r[2] = (__bf16)a.z; r[3] = (__bf16)a.w;
  r[4] = (__bf16)b.x; r[5] = (__bf16)b.y; r[6] = (__bf16)b.z; r[7] = (__bf16)b.w;
  return r;
}
__device__ __forceinline__ bf16x4 cvt4(f32x4 c) {
  bf16x4 r;
  r[0] = (__bf16)c[0]; r[1] = (__bf16)c[1]; r[2] = (__bf16)c[2]; r[3] = (__bf16)c[3];
  return r;
}

// ---------------------------------------------------------------------------
// Weight prep: W1b = [WO1;WI1] bf16 [128 rows][256 k], W2b = [WO2|WI2] bf16
// [256 rows][128 k], b1 = bO1+bI1 (f32[64]), b2 = bO2+bI2 (f32[256]).
// ---------------------------------------------------------------------------
__global__ void wcvt_kernel(
    const float* __restrict__ WO1, const float* __restrict__ WI1,
    const float* __restrict__ WO2, const float* __restrict__ WI2,
    const float* __restrict__ bO1, const float* __restrict__ bI1,
    const float* __restrict__ bO2, const float* __restrict__ bI2,
    unsigned short* __restrict__ W1b, unsigned short* __restrict__ W2b,
    float* __restrict__ b1, float* __restrict__ b2)
{
  const int i = blockIdx.x * 256 + threadIdx.x;   // 0..32767
  { int j = i >> 8, k = i & 255;
    float v = (j < 64) ? WO1[j * 256 + k] : WI1[(j - 64) * 256 + k];
    W1b[i] = f2b(v); }
  { int j = i >> 7, k = i & 127;
    float v = (k < 64) ? WO2[j * 64 + k] : WI2[j * 64 + (k - 64)];
    W2b[i] = f2b(v); }
  if (i < 64)  b1[i] = bO1[i] + bI1[i];
  if (i < 256) b2[i] = bO2[i] + bI2[i];
}

// ---------------------------------------------------------------------------
// gemm0: Yt[gid][j=128][node=32] = (E @ W1cat^T)^T for ALL 8192 graph-sides.
// Pure streaming GEMM: no LDS, no barriers. Block = 64 E-rows (2 graphs);
// wave w: row-half h = w>>1, j-half jh = w&1. bid<2048: subj, else obj.
// ---------------------------------------------------------------------------
__global__ __launch_bounds__(256) void gemm0_kernel(
    const float* __restrict__ subj, const float* __restrict__ obj,
    const unsigned short* __restrict__ W1b, unsigned short* __restrict__ Yt)
{
  const int t = threadIdx.x, w = t >> 6, l = t & 63;
  const int ln16 = l & 15, kg = l >> 4;
  const int h = w >> 1, jh = w & 1;
  const int bid = blockIdx.x;                     // 0..4095
  const float* __restrict__ E = (bid >= 2048) ? obj : subj;
  const size_t row0 = (size_t)(bid & 2047) * 64 + h * 32;

  f32x4 acc[2][4];
  #pragma unroll
  for (int mt = 0; mt < 2; mt++)
    #pragma unroll
    for (int nt = 0; nt < 4; nt++) { f32x4 z = {0.f, 0.f, 0.f, 0.f}; acc[mt][nt] = z; }

  const float* ea = E + (row0 + ln16) * DIM + kg * 8;
  const unsigned short* wb = W1b + (jh * 64 + ln16) * 256 + kg * 8;

  #pragma unroll
  for (int ks = 0; ks < 8; ks++) {
    bf16x8 B[4];
    #pragma unroll
    for (int nt = 0; nt < 4; nt++)
      B[nt] = *(const bf16x8*)(wb + nt * 4096 + ks * 32);
    #pragma unroll
    for (int mt = 0; mt < 2; mt++) {
      float4 a0 = *(const float4*)(ea + mt * 4096 + ks * 32);
      float4 a1 = *(const float4*)(ea + mt * 4096 + ks * 32 + 4);
      bf16x8 A = cvt8(a0, a1);
      #pragma unroll
      for (int nt = 0; nt < 4; nt++)
        acc[mt][nt] = __builtin_amdgcn_mfma_f32_16x16x32_bf16(A, B[nt], acc[mt][nt], 0, 0, 0);
    }
  }
  // C[m=row][n=j] -> Yt[gid][j][node]; gid = bid*2+h, node = mt*16+kg*4+i
  unsigned short* yo = Yt + ((size_t)(bid * 2 + h) * 128 + jh * 64 + ln16) * 32 + kg * 4;
  #pragma unroll
  for (int mt = 0; mt < 2; mt++)
    #pragma unroll
    for (int nt = 0; nt < 4; nt++)
      *(bf16x4*)(yo + nt * 512 + mt * 16) = cvt4(acc[mt][nt]);
}

// ---------------------------------------------------------------------------
// graph_bc: one WAVE per graph-side, no barriers, all state wave-private.
//  counts (packed-byte LDS atomics) -> M frags (regs) -> step1 (B from Yt)
//  -> H1T (LDS) -> step2 -> A2 (LDS) -> step3 (W2 from L2) + fused readout.
// LDS per wave: cnt 1280B + H1T 64x72B (4608) + A2 32x272B (8704) = 14592B.
// ---------------------------------------------------------------------------
__global__ __launch_bounds__(256) void graph_bc_kernel(
    const unsigned short* __restrict__ Yt,
    const int* __restrict__ ssrc, const int* __restrict__ sdst,
    const int* __restrict__ osrc, const int* __restrict__ odst,
    const unsigned short* __restrict__ W2b,
    const float* __restrict__ b1, const float* __restrict__ b2,
    float* __restrict__ gout)
{
  __shared__ __align__(16) unsigned char S[58368];
  const int t = threadIdx.x, w = t >> 6, l = t & 63;
  const int ln16 = l & 15, kg = l >> 4;
  const int gid = blockIdx.x * 4 + w;             // 0..8191
  const int side = gid >> 12, g = gid & (BGR - 1);
  unsigned* cw = (unsigned*)(S + w * 14592);
  unsigned char* h1t = S + w * 14592 + 1280;
  unsigned char* a2  = S + w * 14592 + 5888;

  const int* __restrict__ srcp = side ? osrc : ssrc;
  const int* __restrict__ dstp = side ? odst : sdst;

  // edge loads (issue early)
  const int eb = g * 128 + l;
  const int s0 = srcp[eb] & 31, s1 = srcp[eb + 64] & 31;
  const int d0 = dstp[eb] & 31, d1 = dstp[eb + 64] & 31;

  // step1 B-frags from Yt (issue early; independent of counts)
  const unsigned short* yg = Yt + (size_t)gid * 4096;
  bf16x8 Bo[4], Bi[4];
  #pragma unroll
  for (int nt = 0; nt < 4; nt++) {
    Bo[nt] = *(const bf16x8*)(yg + (nt * 16 + ln16) * 32 + kg * 8);
    Bi[nt] = *(const bf16x8*)(yg + (64 + nt * 16 + ln16) * 32 + kg * 8);
  }
  float b1j[4];
  #pragma unroll
  for (int nt = 0; nt < 4; nt++) b1j[nt] = b1[nt * 16 + ln16];

  // zero counts, then count (wave-synchronous program order; wave-private LDS)
  #pragma unroll
  for (int i = 0; i < 5; i++) cw[l + i * 64] = 0u;
  atomicAdd(&cw[d0 * 8 + (s0 >> 2)], 1u << ((s0 & 3) * 8));
  atomicAdd(&cw[d1 * 8 + (s1 >> 2)], 1u << ((s1 & 3) * 8));
  atomicAdd(&cw[256 + d0], 1u); atomicAdd(&cw[256 + d1], 1u);
  atomicAdd(&cw[288 + s0], 1u); atomicAdd(&cw[288 + s1], 1u);

  // M fragments in registers
  bf16x8 m1f[2], m2f[2];
  #pragma unroll
  for (int hf = 0; hf < 2; hf++) {
    const int r = hf * 16 + ln16;
    const float fi = 1.0f / fmaxf((float)cw[256 + r], 1.0f);
    const float fo = 1.0f / fmaxf((float)cw[288 + r], 1.0f);
    const unsigned w0 = cw[r * 8 + kg * 2], w1 = cw[r * 8 + kg * 2 + 1];
    bf16x8 a, b;
    #pragma unroll
    for (int q = 0; q < 4; q++) {
      a[q]     = (__bf16)((float)((w0 >> (q * 8)) & 255u) * fi);
      a[4 + q] = (__bf16)((float)((w1 >> (q * 8)) & 255u) * fi);
    }
    #pragma unroll
    for (int q = 0; q < 8; q++) {
      const unsigned wq = cw[(kg * 8 + q) * 8 + (r >> 2)];
      b[q] = (__bf16)((float)((wq >> ((r & 3) * 8)) & 255u) * fo);
    }
    m1f[hf] = a; m2f[hf] = b;
  }

  // step1: H1[dst][j64] = relu(M1@Yo + M2@Yi + b1) -> H1T[j][dst] in LDS
  #pragma unroll
  for (int mt = 0; mt < 2; mt++)
    #pragma unroll
    for (int nt = 0; nt < 4; nt++) {
      f32x4 z = {0.f, 0.f, 0.f, 0.f};
      f32x4 c = __builtin_amdgcn_mfma_f32_16x16x32_bf16(m1f[mt], Bo[nt], z, 0, 0, 0);
      c = __builtin_amdgcn_mfma_f32_16x16x32_bf16(m2f[mt], Bi[nt], c, 0, 0, 0);
      f32x4 hv = { fmaxf(c[0] + b1j[nt], 0.f), fmaxf(c[1] + b1j[nt], 0.f),
                   fmaxf(c[2] + b1j[nt], 0.f), fmaxf(c[3] + b1j[nt], 0.f) };
      *(bf16x4*)(h1t + (nt * 16 + ln16) * 72 + (mt * 16 + kg * 4) * 2) = cvt4(hv);
    }

  // step2: A2[dst][128] = [M1@H1 | M2@H1] -> LDS (272B rows)
  #pragma unroll
  for (int mta = 0; mta < 4; mta++) {
    bf16x8 Af = *(const bf16x8*)(h1t + (mta * 16 + ln16) * 72 + kg * 16);
    #pragma unroll
    for (int hf = 0; hf < 2; hf++)
      #pragma unroll
      for (int ntd = 0; ntd < 2; ntd++) {
        f32x4 z = {0.f, 0.f, 0.f, 0.f};
        f32x4 c = __builtin_amdgcn_mfma_f32_16x16x32_bf16(
            Af, hf ? m2f[ntd] : m1f[ntd], z, 0, 0, 0);
        *(bf16x4*)(a2 + (ntd * 16 + ln16) * 272 + hf * 128 + mta * 32 + kg * 8) = cvt4(c);
      }
  }

  // step3: H2 = relu(A2 @ W2cat^T + b2), fused mean over 32 nodes
  bf16x8 BF[2][4];
  #pragma unroll
  for (int ntd = 0; ntd < 2; ntd++)
    #pragma unroll
    for (int ks = 0; ks < 4; ks++)
      BF[ntd][ks] = *(const bf16x8*)(a2 + (ntd * 16 + ln16) * 272 + ks * 64 + kg * 16);

  #pragma unroll
  for (int mt = 0; mt < 16; mt++) {
    bf16x8 AW[4];
    #pragma unroll
    for (int ks = 0; ks < 4; ks++)
      AW[ks] = *(const bf16x8*)(W2b + (mt * 16 + ln16) * 128 + ks * 32 + kg * 8);
    f32x4 a0 = {0.f, 0.f, 0.f, 0.f}, a1 = {0.f, 0.f, 0.f, 0.f};
    #pragma unroll
    for (int ks = 0; ks < 4; ks++) {
      a0 = __builtin_amdgcn_mfma_f32_16x16x32_bf16(AW[ks], BF[0][ks], a0, 0, 0, 0);
      a1 = __builtin_amdgcn_mfma_f32_16x16x32_bf16(AW[ks], BF[1][ks], a1, 0, 0, 0);
    }
    const float4 bb = *(const float4*)(b2 + mt * 16 + kg * 4);
    float v0 = fmaxf(a0[0] + bb.x, 0.f) + fmaxf(a1[0] + bb.x, 0.f);
    float v1 = fmaxf(a0[1] + bb.y, 0.f) + fmaxf(a1[1] + bb.y, 0.f);
    float v2 = fmaxf(a0[2] + bb.z, 0.f) + fmaxf(a1[2] + bb.z, 0.f);
    float v3 = fmaxf(a0[3] + bb.w, 0.f) + fmaxf(a1[3] + bb.w, 0.f);
    #pragma unroll
    for (int d = 1; d < 16; d <<= 1) {
      v0 += __shfl_xor(v0, d); v1 += __shfl_xor(v1, d);
      v2 += __shfl_xor(v2, d); v3 += __shfl_xor(v3, d);
    }
    if (ln16 == 0) {
      float4 o = { v0 * 0.03125f, v1 * 0.03125f, v2 * 0.03125f, v3 * 0.03125f };
      *(float4*)(gout + (size_t)gid * DIM + mt * 16 + kg * 4) = o;
    }
  }
}

// ---------------------------------------------------------------------------
// r_embs = relu(rel @ relW.T + relb). 16 rows per block. (fp32 VALU)
// ---------------------------------------------------------------------------
__global__ __launch_bounds__(256, 4) void rel_kernel(
    const float* __restrict__ rel, const float* __restrict__ relW,
    const float* __restrict__ relb, float* __restrict__ r_out)
{
  __shared__ float srel[16 * HS];
  const int t = threadIdx.x;
  const int b0 = blockIdx.x << 4;
  #pragma unroll
  for (int i = 0; i < 4; i++) {
    int f = (i << 8) + t;
    int r = f >> 6, k4 = f & 63;
    float4 x = *(const float4*)(rel + (size_t)(b0 + r) * DIM + (k4 << 2));
    float* d = &srel[r * HS + (k4 << 2)];
    d[0] = x.x; d[1] = x.y; d[2] = x.z; d[3] = x.w;
  }
  __syncthreads();
  const int r = t & 15, jg = t >> 4;
  const float* pa = &srel[r * HS];
  const float* w = relW + (size_t)(jg * 16) * DIM;
  float acc[16];
  #pragma unroll
  for (int jj = 0; jj < 16; jj++) acc[jj] = 0.f;
  for (int k0 = 0; k0 < DIM; k0 += 16) {
    float a[16];
    #pragma unroll
    for (int u = 0; u < 16; u++) a[u] = pa[k0 + u];
    #pragma unroll
    for (int jj = 0; jj < 16; jj++) {
      const float* wr = w + jj * DIM + k0;
      #pragma unroll
      for (int u = 0; u < 16; u += 4) {
        float4 wv = *(const float4*)(wr + u);
        acc[jj] += a[u]*wv.x + a[u+1]*wv.y + a[u+2]*wv.z + a[u+3]*wv.w;
      }
    }
  }
  float* outp = r_out + (size_t)(b0 + r) * DIM + jg * 16;
  #pragma unroll
  for (int jj = 0; jj < 16; jj++) outp[jj] = fmaxf(acc[jj] + relb[jg * 16 + jj], 0.f);
}

// ---------------------------------------------------------------------------
// Distances: pos = ||h+r-t||, neg = ||h[ch]+r-t[ct]||. One wave per triple.
// ---------------------------------------------------------------------------
__global__ __launch_bounds__(256) void dist_kernel(
    const float* __restrict__ hemb, const float* __restrict__ temb,
    const float* __restrict__ remb, const int* __restrict__ chx,
    const int* __restrict__ ctx, float* __restrict__ out)
{
  const int t = threadIdx.x;
  const int w = t >> 6, l = t & 63;
  const int b = (blockIdx.x << 2) + w;
  float4 h4 = *(const float4*)(hemb + (size_t)b * DIM + (l << 2));
  float4 r4 = *(const float4*)(remb + (size_t)b * DIM + (l << 2));
  float4 t4 = *(const float4*)(temb + (size_t)b * DIM + (l << 2));
  int hb = chx[b], tb = ctx[b];
  float4 hn = *(const float4*)(hemb + (size_t)hb * DIM + (l << 2));
  float4 tn = *(const float4*)(temb + (size_t)tb * DIM + (l << 2));
  float x0 = h4.x + r4.x - t4.x, x1 = h4.y + r4.y - t4.y;
  float x2 = h4.z + r4.z - t4.z, x3 = h4.w + r4.w - t4.w;
  float dp = x0*x0 + x1*x1 + x2*x2 + x3*x3;
  float y0 = hn.x + r4.x - tn.x, y1 = hn.y + r4.y - tn.y;
  float y2 = hn.z + r4.z - tn.z, y3 = hn.w + r4.w - tn.w;
  float dn = y0*y0 + y1*y1 + y2*y2 + y3*y3;
  #pragma unroll
  for (int off = 32; off >= 1; off >>= 1) {
    dp += __shfl_down(dp, off);
    dn += __shfl_down(dn, off);
  }
  if (l == 0) {
    out[b] = sqrtf(dp);
    out[BGR + b] = sqrtf(dn);
  }
}

extern "C" void kernel_launch(void* const* d_in, const int* in_sizes, int n_in,
                              void* d_out, int out_size, void* d_ws, size_t ws_size,
                              hipStream_t stream) {
  const float* subj_embs = (const float*)d_in[0];
  const float* obj_embs  = (const float*)d_in[1];
  const float* rel_tok   = (const float*)d_in[2];
  const int* subj_src = (const int*)d_in[3];
  const int* subj_dst = (const int*)d_in[4];
  const int* obj_src  = (const int*)d_in[5];
  const int* obj_dst  = (const int*)d_in[6];
  // d_in[7] = node_graph_ids (implicit by construction)
  const int* chx = (const int*)d_in[8];
  const int* ctx = (const int*)d_in[9];
  const float* WO1 = (const float*)d_in[10];
  const float* bO1 = (const float*)d_in[11];
  const float* WI1 = (const float*)d_in[12];
  const float* bI1 = (const float*)d_in[13];
  const float* WO2 = (const float*)d_in[14];
  const float* bO2 = (const float*)d_in[15];
  const float* WI2 = (const float*)d_in[16];
  const float* bI2 = (const float*)d_in[17];
  const float* relW = (const float*)d_in[18];
  const float* relb = (const float*)d_in[19];

  float* g_embs = (float*)d_ws;                           // [8192,256] f32 = 8 MB
  float* r_embs = g_embs + (size_t)2 * BGR * DIM;         // [4096,256] f32 = 4 MB
  unsigned short* W1b = (unsigned short*)((char*)d_ws + 12582912);  // 64 KB
  unsigned short* W2b = W1b + 32768;                                // 64 KB
  float* b1 = (float*)((char*)d_ws + 12713984);                     // 256 B
  float* b2 = b1 + 64;                                              // 1 KB
  unsigned short* Yt = (unsigned short*)((char*)d_ws + 16777216);   // 64 MB
  float* out = (float*)d_out;                             // [8192]: pos | neg

  wcvt_kernel<<<128, 256, 0, stream>>>(WO1, WI1, WO2, WI2, bO1, bI1, bO2, bI2,
                                       W1b, W2b, b1, b2);
  gemm0_kernel<<<4096, 256, 0, stream>>>(subj_embs, obj_embs, W1b, Yt);
  graph_bc_kernel<<<2048, 256, 0, stream>>>(
      Yt, subj_src, subj_dst, obj_src, obj_dst, W2b, b1, b2, g_embs);
  rel_kernel<<<BGR / 16, 256, 0, stream>>>(rel_tok, relW, relb, r_embs);
  dist_kernel<<<BGR / 4, 256, 0, stream>>>(
      g_embs, g_embs + (size_t)BGR * DIM, r_embs, chx, ctx, out);
}

// Round 7
// 281.213 us; speedup vs baseline: 1.3416x; 1.0377x over previous
//
#include <hip/hip_runtime.h>
#include <hip/hip_bf16.h>

#define BGR 4096      // graphs per side
#define DIM 256
#define HS  257       // LDS row stride for rel_kernel (fp32)

typedef __bf16 bf16x8 __attribute__((ext_vector_type(8)));
typedef __bf16 bf16x4 __attribute__((ext_vector_type(4)));
typedef float  f32x4  __attribute__((ext_vector_type(4)));

__device__ __forceinline__ unsigned short f2b(float f) {
  unsigned u = __builtin_bit_cast(unsigned, f);
  u = (u + 0x7FFFu + ((u >> 16) & 1u)) >> 16;   // RNE
  return (unsigned short)u;
}

__device__ __forceinline__ bf16x8 cvt8(float4 a, float4 b) {
  bf16x8 r;
  r[0] = (__bf16)a.x; r[1] = (__bf16)a.y; r[2] = (__bf16)a.z; r[3] = (__bf16)a.w;
  r[4] = (__bf16)b.x; r[5] = (__bf16)b.y; r[6] = (__bf16)b.z; r[7] = (__bf16)b.w;
  return r;
}
__device__ __forceinline__ bf16x4 cvt4(f32x4 c) {
  bf16x4 r;
  r[0] = (__bf16)c[0]; r[1] = (__bf16)c[1]; r[2] = (__bf16)c[2]; r[3] = (__bf16)c[3];
  return r;
}

// ---------------------------------------------------------------------------
// Weight prep: W1b = [WO1;WI1] bf16 [128 rows][256 k], W2b = [WO2|WI2] bf16
// [256 rows][128 k], b1 = bO1+bI1 (f32[64]), b2 = bO2+bI2 (f32[256]).
// ---------------------------------------------------------------------------
__global__ void wcvt_kernel(
    const float* __restrict__ WO1, const float* __restrict__ WI1,
    const float* __restrict__ WO2, const float* __restrict__ WI2,
    const float* __restrict__ bO1, const float* __restrict__ bI1,
    const float* __restrict__ bO2, const float* __restrict__ bI2,
    unsigned short* __restrict__ W1b, unsigned short* __restrict__ W2b,
    float* __restrict__ b1, float* __restrict__ b2)
{
  const int i = blockIdx.x * 256 + threadIdx.x;   // 0..32767
  { int j = i >> 8, k = i & 255;
    float v = (j < 64) ? WO1[j * 256 + k] : WI1[(j - 64) * 256 + k];
    W1b[i] = f2b(v); }
  { int j = i >> 7, k = i & 127;
    float v = (k < 64) ? WO2[j * 64 + k] : WI2[j * 64 + (k - 64)];
    W2b[i] = f2b(v); }
  if (i < 64)  b1[i] = bO1[i] + bI1[i];
  if (i < 256) b2[i] = bO2[i] + bI2[i];
}

// ---------------------------------------------------------------------------
// gemm0: Yt[gid][j=128][node=32] = (E @ W1cat^T)^T for ALL 8192 graph-sides.
// No LDS, no barriers. Block = 64 E-rows (2 graphs); wave w: row-half h=w>>1,
// j-half jh=w&1. STAGED: all 32 per-lane A loads issued before any compute
// (MLP >> HBM latency-bandwidth product).
// ---------------------------------------------------------------------------
__global__ __launch_bounds__(256) void gemm0_kernel(
    const float* __restrict__ subj, const float* __restrict__ obj,
    const unsigned short* __restrict__ W1b, unsigned short* __restrict__ Yt)
{
  const int t = threadIdx.x, w = t >> 6, l = t & 63;
  const int ln16 = l & 15, kg = l >> 4;
  const int h = w >> 1, jh = w & 1;
  const int bid = blockIdx.x;                     // 0..4095
  const float* __restrict__ E = (bid >= 2048) ? obj : subj;
  const size_t row0 = (size_t)(bid & 2047) * 64 + h * 32;
  const float* ea = E + (row0 + ln16) * DIM + kg * 8;

  // ---- stage ALL A data: 32 independent dwordx4 loads, issued together ----
  float4 ar[32];
  #pragma unroll
  for (int mt = 0; mt < 2; mt++)
    #pragma unroll
    for (int ks = 0; ks < 8; ks++) {
      ar[(mt * 8 + ks) * 2 + 0] = *(const float4*)(ea + mt * 4096 + ks * 32);
      ar[(mt * 8 + ks) * 2 + 1] = *(const float4*)(ea + mt * 4096 + ks * 32 + 4);
    }
  bf16x8 A[16];
  #pragma unroll
  for (int i = 0; i < 16; i++) A[i] = cvt8(ar[2 * i], ar[2 * i + 1]);

  f32x4 acc[2][4];
  #pragma unroll
  for (int mt = 0; mt < 2; mt++)
    #pragma unroll
    for (int nt = 0; nt < 4; nt++) { f32x4 z = {0.f, 0.f, 0.f, 0.f}; acc[mt][nt] = z; }

  const unsigned short* wb = W1b + (jh * 64 + ln16) * 256 + kg * 8;
  #pragma unroll
  for (int ks = 0; ks < 8; ks++) {
    bf16x8 B[4];
    #pragma unroll
    for (int nt = 0; nt < 4; nt++)
      B[nt] = *(const bf16x8*)(wb + nt * 4096 + ks * 32);
    #pragma unroll
    for (int mt = 0; mt < 2; mt++)
      #pragma unroll
      for (int nt = 0; nt < 4; nt++)
        acc[mt][nt] = __builtin_amdgcn_mfma_f32_16x16x32_bf16(
            A[mt * 8 + ks], B[nt], acc[mt][nt], 0, 0, 0);
  }
  // C[m=row][n=j] -> Yt[gid][j][node]; gid = bid*2+h, node = mt*16+kg*4+i
  unsigned short* yo = Yt + ((size_t)(bid * 2 + h) * 128 + jh * 64 + ln16) * 32 + kg * 4;
  #pragma unroll
  for (int mt = 0; mt < 2; mt++)
    #pragma unroll
    for (int nt = 0; nt < 4; nt++)
      *(bf16x4*)(yo + nt * 512 + mt * 16) = cvt4(acc[mt][nt]);
}

// ---------------------------------------------------------------------------
// graph_bc: one WAVE per graph-side, no barriers, all state wave-private.
// LDS per wave (13312B): H1T 64x72B at [0,4608); A2 32x272B at [4608,13312),
// with the count buffer (1280B) ALIASED at the start of A2 (counts die
// before A2 is written; wave-private LDS is in program order).
// 53248B/block -> 3 blocks/CU.
// ---------------------------------------------------------------------------
__global__ __launch_bounds__(256) void graph_bc_kernel(
    const unsigned short* __restrict__ Yt,
    const int* __restrict__ ssrc, const int* __restrict__ sdst,
    const int* __restrict__ osrc, const int* __restrict__ odst,
    const unsigned short* __restrict__ W2b,
    const float* __restrict__ b1, const float* __restrict__ b2,
    float* __restrict__ gout)
{
  __shared__ __align__(16) unsigned char S[53248];
  const int t = threadIdx.x, w = t >> 6, l = t & 63;
  const int ln16 = l & 15, kg = l >> 4;
  const int gid = blockIdx.x * 4 + w;             // 0..8191
  const int side = gid >> 12, g = gid & (BGR - 1);
  unsigned char* h1t = S + w * 13312;
  unsigned char* a2  = S + w * 13312 + 4608;
  unsigned* cw = (unsigned*)a2;                   // aliased; dead before a2 writes

  const int* __restrict__ srcp = side ? osrc : ssrc;
  const int* __restrict__ dstp = side ? odst : sdst;

  // edge loads (issue early)
  const int eb = g * 128 + l;
  const int s0 = srcp[eb] & 31, s1 = srcp[eb + 64] & 31;
  const int d0 = dstp[eb] & 31, d1 = dstp[eb + 64] & 31;

  // step1 B-frags from Yt (issue early; independent of counts)
  const unsigned short* yg = Yt + (size_t)gid * 4096;
  bf16x8 Bo[4], Bi[4];
  #pragma unroll
  for (int nt = 0; nt < 4; nt++) {
    Bo[nt] = *(const bf16x8*)(yg + (nt * 16 + ln16) * 32 + kg * 8);
    Bi[nt] = *(const bf16x8*)(yg + (64 + nt * 16 + ln16) * 32 + kg * 8);
  }
  float b1j[4];
  #pragma unroll
  for (int nt = 0; nt < 4; nt++) b1j[nt] = b1[nt * 16 + ln16];

  // zero counts, then count (wave-synchronous program order; wave-private LDS)
  #pragma unroll
  for (int i = 0; i < 5; i++) cw[l + i * 64] = 0u;
  atomicAdd(&cw[d0 * 8 + (s0 >> 2)], 1u << ((s0 & 3) * 8));
  atomicAdd(&cw[d1 * 8 + (s1 >> 2)], 1u << ((s1 & 3) * 8));
  atomicAdd(&cw[256 + d0], 1u); atomicAdd(&cw[256 + d1], 1u);
  atomicAdd(&cw[288 + s0], 1u); atomicAdd(&cw[288 + s1], 1u);

  // M fragments in registers
  bf16x8 m1f[2], m2f[2];
  #pragma unroll
  for (int hf = 0; hf < 2; hf++) {
    const int r = hf * 16 + ln16;
    const float fi = 1.0f / fmaxf((float)cw[256 + r], 1.0f);
    const float fo = 1.0f / fmaxf((float)cw[288 + r], 1.0f);
    const unsigned w0 = cw[r * 8 + kg * 2], w1 = cw[r * 8 + kg * 2 + 1];
    bf16x8 a, b;
    #pragma unroll
    for (int q = 0; q < 4; q++) {
      a[q]     = (__bf16)((float)((w0 >> (q * 8)) & 255u) * fi);
      a[4 + q] = (__bf16)((float)((w1 >> (q * 8)) & 255u) * fi);
    }
    #pragma unroll
    for (int q = 0; q < 8; q++) {
      const unsigned wq = cw[(kg * 8 + q) * 8 + (r >> 2)];
      b[q] = (__bf16)((float)((wq >> ((r & 3) * 8)) & 255u) * fo);
    }
    m1f[hf] = a; m2f[hf] = b;
  }

  // step1: H1[dst][j64] = relu(M1@Yo + M2@Yi + b1) -> H1T[j][dst] in LDS
  #pragma unroll
  for (int mt = 0; mt < 2; mt++)
    #pragma unroll
    for (int nt = 0; nt < 4; nt++) {
      f32x4 z = {0.f, 0.f, 0.f, 0.f};
      f32x4 c = __builtin_amdgcn_mfma_f32_16x16x32_bf16(m1f[mt], Bo[nt], z, 0, 0, 0);
      c = __builtin_amdgcn_mfma_f32_16x16x32_bf16(m2f[mt], Bi[nt], c, 0, 0, 0);
      f32x4 hv = { fmaxf(c[0] + b1j[nt], 0.f), fmaxf(c[1] + b1j[nt], 0.f),
                   fmaxf(c[2] + b1j[nt], 0.f), fmaxf(c[3] + b1j[nt], 0.f) };
      *(bf16x4*)(h1t + (nt * 16 + ln16) * 72 + (mt * 16 + kg * 4) * 2) = cvt4(hv);
    }

  // step2: A2[dst][128] = [M1@H1 | M2@H1] -> LDS (272B rows; overwrites cw)
  #pragma unroll
  for (int mta = 0; mta < 4; mta++) {
    bf16x8 Af = *(const bf16x8*)(h1t + (mta * 16 + ln16) * 72 + kg * 16);
    #pragma unroll
    for (int hf = 0; hf < 2; hf++)
      #pragma unroll
      for (int ntd = 0; ntd < 2; ntd++) {
        f32x4 z = {0.f, 0.f, 0.f, 0.f};
        f32x4 c = __builtin_amdgcn_mfma_f32_16x16x32_bf16(
            Af, hf ? m2f[ntd] : m1f[ntd], z, 0, 0, 0);
        *(bf16x4*)(a2 + (ntd * 16 + ln16) * 272 + hf * 128 + mta * 32 + kg * 8) = cvt4(c);
      }
  }

  // step3: H2 = relu(A2 @ W2cat^T + b2), fused mean over 32 nodes
  bf16x8 BF[2][4];
  #pragma unroll
  for (int ntd = 0; ntd < 2; ntd++)
    #pragma unroll
    for (int ks = 0; ks < 4; ks++)
      BF[ntd][ks] = *(const bf16x8*)(a2 + (ntd * 16 + ln16) * 272 + ks * 64 + kg * 16);

  #pragma unroll
  for (int mt = 0; mt < 16; mt++) {
    bf16x8 AW[4];
    #pragma unroll
    for (int ks = 0; ks < 4; ks++)
      AW[ks] = *(const bf16x8*)(W2b + (mt * 16 + ln16) * 128 + ks * 32 + kg * 8);
    f32x4 a0 = {0.f, 0.f, 0.f, 0.f}, a1 = {0.f, 0.f, 0.f, 0.f};
    #pragma unroll
    for (int ks = 0; ks < 4; ks++) {
      a0 = __builtin_amdgcn_mfma_f32_16x16x32_bf16(AW[ks], BF[0][ks], a0, 0, 0, 0);
      a1 = __builtin_amdgcn_mfma_f32_16x16x32_bf16(AW[ks], BF[1][ks], a1, 0, 0, 0);
    }
    const float4 bb = *(const float4*)(b2 + mt * 16 + kg * 4);
    float v0 = fmaxf(a0[0] + bb.x, 0.f) + fmaxf(a1[0] + bb.x, 0.f);
    float v1 = fmaxf(a0[1] + bb.y, 0.f) + fmaxf(a1[1] + bb.y, 0.f);
    float v2 = fmaxf(a0[2] + bb.z, 0.f) + fmaxf(a1[2] + bb.z, 0.f);
    float v3 = fmaxf(a0[3] + bb.w, 0.f) + fmaxf(a1[3] + bb.w, 0.f);
    #pragma unroll
    for (int d = 1; d < 16; d <<= 1) {
      v0 += __shfl_xor(v0, d); v1 += __shfl_xor(v1, d);
      v2 += __shfl_xor(v2, d); v3 += __shfl_xor(v3, d);
    }
    if (ln16 == 0) {
      float4 o = { v0 * 0.03125f, v1 * 0.03125f, v2 * 0.03125f, v3 * 0.03125f };
      *(float4*)(gout + (size_t)gid * DIM + mt * 16 + kg * 4) = o;
    }
  }
}

// ---------------------------------------------------------------------------
// r_embs = relu(rel @ relW.T + relb). 16 rows per block. (fp32 VALU)
// ---------------------------------------------------------------------------
__global__ __launch_bounds__(256, 4) void rel_kernel(
    const float* __restrict__ rel, const float* __restrict__ relW,
    const float* __restrict__ relb, float* __restrict__ r_out)
{
  __shared__ float srel[16 * HS];
  const int t = threadIdx.x;
  const int b0 = blockIdx.x << 4;
  #pragma unroll
  for (int i = 0; i < 4; i++) {
    int f = (i << 8) + t;
    int r = f >> 6, k4 = f & 63;
    float4 x = *(const float4*)(rel + (size_t)(b0 + r) * DIM + (k4 << 2));
    float* d = &srel[r * HS + (k4 << 2)];
    d[0] = x.x; d[1] = x.y; d[2] = x.z; d[3] = x.w;
  }
  __syncthreads();
  const int r = t & 15, jg = t >> 4;
  const float* pa = &srel[r * HS];
  const float* w = relW + (size_t)(jg * 16) * DIM;
  float acc[16];
  #pragma unroll
  for (int jj = 0; jj < 16; jj++) acc[jj] = 0.f;
  for (int k0 = 0; k0 < DIM; k0 += 16) {
    float a[16];
    #pragma unroll
    for (int u = 0; u < 16; u++) a[u] = pa[k0 + u];
    #pragma unroll
    for (int jj = 0; jj < 16; jj++) {
      const float* wr = w + jj * DIM + k0;
      #pragma unroll
      for (int u = 0; u < 16; u += 4) {
        float4 wv = *(const float4*)(wr + u);
        acc[jj] += a[u]*wv.x + a[u+1]*wv.y + a[u+2]*wv.z + a[u+3]*wv.w;
      }
    }
  }
  float* outp = r_out + (size_t)(b0 + r) * DIM + jg * 16;
  #pragma unroll
  for (int jj = 0; jj < 16; jj++) outp[jj] = fmaxf(acc[jj] + relb[jg * 16 + jj], 0.f);
}

// ---------------------------------------------------------------------------
// Distances: pos = ||h+r-t||, neg = ||h[ch]+r-t[ct]||. One wave per triple.
// ---------------------------------------------------------------------------
__global__ __launch_bounds__(256) void dist_kernel(
    const float* __restrict__ hemb, const float* __restrict__ temb,
    const float* __restrict__ remb, const int* __restrict__ chx,
    const int* __restrict__ ctx, float* __restrict__ out)
{
  const int t = threadIdx.x;
  const int w = t >> 6, l = t & 63;
  const int b = (blockIdx.x << 2) + w;
  float4 h4 = *(const float4*)(hemb + (size_t)b * DIM + (l << 2));
  float4 r4 = *(const float4*)(remb + (size_t)b * DIM + (l << 2));
  float4 t4 = *(const float4*)(temb + (size_t)b * DIM + (l << 2));
  int hb = chx[b], tb = ctx[b];
  float4 hn = *(const float4*)(hemb + (size_t)hb * DIM + (l << 2));
  float4 tn = *(const float4*)(temb + (size_t)tb * DIM + (l << 2));
  float x0 = h4.x + r4.x - t4.x, x1 = h4.y + r4.y - t4.y;
  float x2 = h4.z + r4.z - t4.z, x3 = h4.w + r4.w - t4.w;
  float dp = x0*x0 + x1*x1 + x2*x2 + x3*x3;
  float y0 = hn.x + r4.x - tn.x, y1 = hn.y + r4.y - tn.y;
  float y2 = hn.z + r4.z - tn.z, y3 = hn.w + r4.w - tn.w;
  float dn = y0*y0 + y1*y1 + y2*y2 + y3*y3;
  #pragma unroll
  for (int off = 32; off >= 1; off >>= 1) {
    dp += __shfl_down(dp, off);
    dn += __shfl_down(dn, off);
  }
  if (l == 0) {
    out[b] = sqrtf(dp);
    out[BGR + b] = sqrtf(dn);
  }
}

extern "C" void kernel_launch(void* const* d_in, const int* in_sizes, int n_in,
                              void* d_out, int out_size, void* d_ws, size_t ws_size,
                              hipStream_t stream) {
  const float* subj_embs = (const float*)d_in[0];
  const float* obj_embs  = (const float*)d_in[1];
  const float* rel_tok   = (const float*)d_in[2];
  const int* subj_src = (const int*)d_in[3];
  const int* subj_dst = (const int*)d_in[4];
  const int* obj_src  = (const int*)d_in[5];
  const int* obj_dst  = (const int*)d_in[6];
  // d_in[7] = node_graph_ids (implicit by construction)
  const int* chx = (const int*)d_in[8];
  const int* ctx = (const int*)d_in[9];
  const float* WO1 = (const float*)d_in[10];
  const float* bO1 = (const float*)d_in[11];
  const float* WI1 = (const float*)d_in[12];
  const float* bI1 = (const float*)d_in[13];
  const float* WO2 = (const float*)d_in[14];
  const float* bO2 = (const float*)d_in[15];
  const float* WI2 = (const float*)d_in[16];
  const float* bI2 = (const float*)d_in[17];
  const float* relW = (const float*)d_in[18];
  const float* relb = (const float*)d_in[19];

  float* g_embs = (float*)d_ws;                           // [8192,256] f32 = 8 MB
  float* r_embs = g_embs + (size_t)2 * BGR * DIM;         // [4096,256] f32 = 4 MB
  unsigned short* W1b = (unsigned short*)((char*)d_ws + 12582912);  // 64 KB
  unsigned short* W2b = W1b + 32768;                                // 64 KB
  float* b1 = (float*)((char*)d_ws + 12713984);                     // 256 B
  float* b2 = b1 + 64;                                              // 1 KB
  unsigned short* Yt = (unsigned short*)((char*)d_ws + 16777216);   // 64 MB
  float* out = (float*)d_out;                             // [8192]: pos | neg

  wcvt_kernel<<<128, 256, 0, stream>>>(WO1, WI1, WO2, WI2, bO1, bI1, bO2, bI2,
                                       W1b, W2b, b1, b2);
  gemm0_kernel<<<4096, 256, 0, stream>>>(subj_embs, obj_embs, W1b, Yt);
  graph_bc_kernel<<<2048, 256, 0, stream>>>(
      Yt, subj_src, subj_dst, obj_src, obj_dst, W2b, b1, b2, g_embs);
  rel_kernel<<<BGR / 16, 256, 0, stream>>>(rel_tok, relW, relb, r_embs);
  dist_kernel<<<BGR / 4, 256, 0, stream>>>(
      g_embs, g_embs + (size_t)BGR * DIM, r_embs, chx, ctx, out);
}